// Round 6
// baseline (244.808 us; speedup 1.0000x reference)
//
#include <hip/hip_runtime.h>
#include <math.h>

#define N_AA    20
#define NATOM   15
#define D_FEAT  128
#define TM      8
#define W1_N    256
#define ROW_COORD 128
#define ROW_DIH   1028
#define ROW_CHAIN 1067
#define MAXBL   16384
#define MAXBLK  (MAXBL / TM + N_AA)   // 2068
#define NWAVE   16

// ---------------- prep: blocks 0..29 = tables, block 30 = counting sort ----------------
__global__ __launch_bounds__(1024) void prep_kernel(
    const int* __restrict__ seq, const float* __restrict__ aa_emb,
    const float* __restrict__ chain_emb, const float* __restrict__ W1,
    int BL,
    float* __restrict__ aaT, float* __restrict__ chT,
    int* __restrict__ bucket_start, int* __restrict__ blk_type,
    int* __restrict__ blk_chunk, int* __restrict__ rowidx)
{
    const int t = threadIdx.x;
    const int b = blockIdx.x;

    if (b < 30) {
        if (t < W1_N) {
            if (b < N_AA) {
                const float* e = aa_emb + b * D_FEAT;
                float acc = 0.f;
                #pragma unroll 8
                for (int k = 0; k < D_FEAT; ++k)
                    acc += e[k] * W1[(size_t)k * W1_N + t];
                aaT[b * W1_N + t] = acc;
            } else {
                const int c = b - N_AA;
                const float* e = chain_emb + c * D_FEAT;
                float acc = 0.f;
                #pragma unroll 8
                for (int k = 0; k < D_FEAT; ++k)
                    acc += e[k] * W1[(size_t)(ROW_CHAIN + k) * W1_N + t];
                chT[c * W1_N + t] = acc;
            }
        }
        return;
    }

    // ---- block 30: counting sort of rows by aa type (parallelized) ----
    __shared__ int sseq[MAXBL];
    __shared__ int hist[NWAVE][N_AA];    // per-wave histograms
    __shared__ int wcur[NWAVE][N_AA];    // per-wave scatter cursors
    __shared__ int bs[N_AA + 1];         // bucket starts (rows)
    __shared__ int blkoff[N_AA + 1];     // block-table offsets per type

    const int w = t >> 6;

    for (int i = t; i < BL; i += 1024) sseq[i] = seq[i];
    if (t < NWAVE * N_AA) hist[t / N_AA][t % N_AA] = 0;
    __syncthreads();

    for (int i = t; i < BL; i += 1024) atomicAdd(&hist[w][sseq[i]], 1);
    __syncthreads();

    if (t == 0) {
        int runr = 0, runb = 0;
        for (int g = 0; g < N_AA; ++g) {
            int s = 0;
            #pragma unroll
            for (int ww = 0; ww < NWAVE; ++ww) s += hist[ww][g];
            bs[g] = runr; runr += s;
            blkoff[g] = runb; runb += (s + TM - 1) / TM;
        }
        bs[N_AA] = runr;
        blkoff[N_AA] = runb;
    }
    __syncthreads();

    if (t <= N_AA) bucket_start[t] = bs[t];

    if (t < NWAVE * N_AA) {
        const int w2 = t / N_AA, g2 = t % N_AA;
        int o = bs[g2];
        for (int ww = 0; ww < w2; ++ww) o += hist[ww][g2];
        wcur[w2][g2] = o;
    }

    const int nblk = blkoff[N_AA];
    for (int i = t; i < MAXBLK; i += 1024) {
        if (i < nblk) {
            int g = 0;
            while (blkoff[g + 1] <= i) ++g;    // <=20 steps
            blk_type[i]  = g;
            blk_chunk[i] = i - blkoff[g];
        } else {
            blk_type[i] = -1;
        }
    }
    __syncthreads();

    for (int i = t; i < BL; i += 1024) {
        const int pos = atomicAdd(&wcur[w][sseq[i]], 1);
        rowidx[pos] = i;
    }
}

__device__ __forceinline__ float4 relu4(float4 v) {
    float4 o;
    o.x = fmaxf(v.x, 0.f); o.y = fmaxf(v.y, 0.f);
    o.z = fmaxf(v.z, 0.f); o.w = fmaxf(v.w, 0.f);
    return o;
}

// ---------------- fused: features + 4-layer MLP, 8 same-type rows per block ----------------
__global__ __launch_bounds__(256, 6) void fused_kernel(
    const int* __restrict__ chain_idx, const float* __restrict__ xyz,
    const float* __restrict__ dihedrals, const float* __restrict__ orientation,
    const float* __restrict__ W1, const float* __restrict__ b1,
    const float* __restrict__ W2, const float* __restrict__ b2,
    const float* __restrict__ W3, const float* __restrict__ b3,
    const float* __restrict__ W4, const float* __restrict__ b4,
    const float* __restrict__ aaT, const float* __restrict__ chT,
    const int* __restrict__ bucket_start, const int* __restrict__ blk_type,
    const int* __restrict__ blk_chunk, const int* __restrict__ rowidx,
    float* __restrict__ out)
{
    __shared__ __align__(16) float bufA[TM][128];   // feat (uses [0..87]) then h2
    __shared__ __align__(16) float bufB[TM][256];   // h1 then h3
    __shared__ int s_row[TM];
    __shared__ int s_rowld[TM];
    __shared__ int s_chain[TM];

    float (*feat)[128] = bufA;
    float (*h1)[256]   = bufB;
    float (*h2)[128]   = bufA;
    float (*h3)[128]   = (float(*)[128])bufB;

    const int t = threadIdx.x;
    const int g = blk_type[blockIdx.x];
    if (g < 0) return;
    const int chunk  = blk_chunk[blockIdx.x];
    const int bstart = bucket_start[g] + chunk * TM;
    const int nrows  = min(TM, bucket_start[g + 1] - bstart);

    if (t < TM) {
        const bool valid = (t < nrows);
        const int rl = rowidx[valid ? (bstart + t) : bstart];
        s_row[t]   = valid ? rl : -1;
        s_rowld[t] = rl;
        s_chain[t] = chain_idx[rl];
        feat[t][45] = 0.f; feat[t][46] = 0.f; feat[t][47] = 0.f;  // coord pad
        feat[t][87] = 0.f;                                        // dihedral pad
    }
    __syncthreads();

    // ---- coord features: xyz_local = O^T (xyz - CA) ----
    if (t < TM * NATOM) {
        const int r = t / NATOM, a = t % NATOM;
        const int rl = s_rowld[r];
        const float* xr = xyz + (size_t)rl * (NATOM * 3);
        const float cax = xr[3], cay = xr[4], caz = xr[5];   // CA_IDX = 1
        const float rx = xr[a*3+0] - cax;
        const float ry = xr[a*3+1] - cay;
        const float rz = xr[a*3+2] - caz;
        const float* O = orientation + (size_t)rl * 9;
        feat[r][a*3+0] = O[0]*rx + O[3]*ry + O[6]*rz;
        feat[r][a*3+1] = O[1]*rx + O[4]*ry + O[7]*rz;
        feat[r][a*3+2] = O[2]*rx + O[5]*ry + O[8]*rz;
    }

    // ---- dihedral angular encoding ----
    if (t < TM * 3) {
        const int r = t / 3, d = t % 3;
        const float x = dihedrals[(size_t)s_rowld[r] * 3 + d];
        float* f = &feat[r][48 + d * 13];
        const float F3 = (float)(1.0 / 3.0);
        f[0]  = x;
        f[1]  = sinf(1.0f * x); f[2]  = sinf(2.0f * x); f[3]  = sinf(3.0f * x);
        f[4]  = sinf(1.0f * x); f[5]  = sinf(0.5f * x); f[6]  = sinf(F3 * x);
        f[7]  = cosf(1.0f * x); f[8]  = cosf(2.0f * x); f[9]  = cosf(3.0f * x);
        f[10] = cosf(1.0f * x); f[11] = cosf(0.5f * x); f[12] = cosf(F3 * x);
    }
    __syncthreads();

    // ---- layer 1: partials in registers across the two weight phases ----
    {
        float acc[TM];
        // phase A: coord (48 weight regs live)
        {
            float wc[48];
            #pragma unroll
            for (int k = 0; k < 48; ++k)
                wc[k] = W1[(size_t)(ROW_COORD + g * 45 + k) * W1_N + t];
            #pragma unroll
            for (int r = 0; r < TM; ++r) {
                const float4* f4 = (const float4*)&feat[r][0];
                float a0 = 0.f, a1 = 0.f;
                #pragma unroll
                for (int k4 = 0; k4 < 12; k4 += 2) {
                    const float4 fa = f4[k4], fb = f4[k4+1];
                    a0 += fa.x * wc[k4*4+0]; a0 += fa.y * wc[k4*4+1];
                    a0 += fa.z * wc[k4*4+2]; a0 += fa.w * wc[k4*4+3];
                    a1 += fb.x * wc[k4*4+4]; a1 += fb.y * wc[k4*4+5];
                    a1 += fb.z * wc[k4*4+6]; a1 += fb.w * wc[k4*4+7];
                }
                acc[r] = a0 + a1;
            }
        }
        // phase B: dihedral + base + relu (40 weight regs live)
        {
            float wd[40];
            #pragma unroll
            for (int k = 0; k < 40; ++k)
                wd[k] = W1[(size_t)(ROW_DIH + k) * W1_N + t];
            const float base = b1[t] + aaT[g * W1_N + t];
            #pragma unroll
            for (int r = 0; r < TM; ++r) {
                const float4* fd4 = (const float4*)&feat[r][48];
                float a0 = base + chT[s_chain[r] * W1_N + t] + acc[r];
                float a1 = 0.f;
                #pragma unroll
                for (int k4 = 0; k4 < 10; k4 += 2) {
                    const float4 fa = fd4[k4], fb = fd4[k4+1];
                    a0 += fa.x * wd[k4*4+0]; a0 += fa.y * wd[k4*4+1];
                    a0 += fa.z * wd[k4*4+2]; a0 += fa.w * wd[k4*4+3];
                    a1 += fb.x * wd[k4*4+4]; a1 += fb.y * wd[k4*4+5];
                    a1 += fb.z * wd[k4*4+6]; a1 += fb.w * wd[k4*4+7];
                }
                h1[r][t] = fmaxf(a0 + a1, 0.f);
            }
        }
    }
    __syncthreads();   // h1 complete; feat dead -> h2 may overwrite bufA

    const int r0 = t >> 5;          // 0..7 : one row per 32-lane group
    const int j0 = (t & 31) * 4;    // 4 cols per thread

    // ---- layer 2: h2 = relu(h1 @ W2 + b2), K=256 ----
    {
        float4 c0 = *(const float4*)&b2[j0];
        for (int k = 0; k < 256; k += 4) {
            float a0v[4];
            *(float4*)a0v = *(const float4*)&h1[r0][k];
            #pragma unroll
            for (int kk = 0; kk < 4; ++kk) {
                const float4 wv = *(const float4*)&W2[(size_t)(k+kk)*128 + j0];
                c0.x += a0v[kk]*wv.x; c0.y += a0v[kk]*wv.y; c0.z += a0v[kk]*wv.z; c0.w += a0v[kk]*wv.w;
            }
        }
        __syncthreads();   // all reads of bufA(feat)/h1 done before h2 overwrites bufA
        *(float4*)&h2[r0][j0] = relu4(c0);
    }
    __syncthreads();   // h2 complete; h1 dead -> h3 may overwrite bufB

    // ---- layer 3: h3 = relu(h2 @ W3 + b3), K=128 ----
    {
        float4 c0 = *(const float4*)&b3[j0];
        for (int k = 0; k < 128; k += 4) {
            float a0v[4];
            *(float4*)a0v = *(const float4*)&h2[r0][k];
            #pragma unroll
            for (int kk = 0; kk < 4; ++kk) {
                const float4 wv = *(const float4*)&W3[(size_t)(k+kk)*128 + j0];
                c0.x += a0v[kk]*wv.x; c0.y += a0v[kk]*wv.y; c0.z += a0v[kk]*wv.z; c0.w += a0v[kk]*wv.w;
            }
        }
        *(float4*)&h3[r0][j0] = relu4(c0);
    }
    __syncthreads();   // h3 complete

    // ---- layer 4: out = h3 @ W4 + b4, scatter to original rows ----
    {
        float4 c0 = *(const float4*)&b4[j0];
        for (int k = 0; k < 128; k += 4) {
            float a0v[4];
            *(float4*)a0v = *(const float4*)&h3[r0][k];
            #pragma unroll
            for (int kk = 0; kk < 4; ++kk) {
                const float4 wv = *(const float4*)&W4[(size_t)(k+kk)*128 + j0];
                c0.x += a0v[kk]*wv.x; c0.y += a0v[kk]*wv.y; c0.z += a0v[kk]*wv.z; c0.w += a0v[kk]*wv.w;
            }
        }
        const int o0 = s_row[r0];
        if (o0 >= 0) *(float4*)&out[(size_t)o0 * 128 + j0] = c0;
    }
}

extern "C" void kernel_launch(void* const* d_in, const int* in_sizes, int n_in,
                              void* d_out, int out_size, void* d_ws, size_t ws_size,
                              hipStream_t stream) {
    const int*   seq    = (const int*)d_in[0];
    const float* xyz    = (const float*)d_in[1];
    const float* dihed  = (const float*)d_in[2];
    const int*   chain  = (const int*)d_in[3];
    const float* orient = (const float*)d_in[4];
    // d_in[5] = atom_mask: unused by the reference
    const float* aa_emb = (const float*)d_in[6];
    const float* ch_emb = (const float*)d_in[7];
    const float* W1 = (const float*)d_in[8];
    const float* b1 = (const float*)d_in[9];
    const float* W2 = (const float*)d_in[10];
    const float* b2 = (const float*)d_in[11];
    const float* W3 = (const float*)d_in[12];
    const float* b3 = (const float*)d_in[13];
    const float* W4 = (const float*)d_in[14];
    const float* b4 = (const float*)d_in[15];
    float* out = (float*)d_out;

    const int BL = in_sizes[0];           // 16384 rows

    // workspace layout
    float* aaT = (float*)d_ws;                       // 20*256
    float* chT = aaT + N_AA * W1_N;                  // 10*256
    int* bucket_start = (int*)(chT + 10 * W1_N);     // 32
    int* blk_type     = bucket_start + 32;           // MAXBLK
    int* blk_chunk    = blk_type + MAXBLK;           // MAXBLK
    int* rowidx       = blk_chunk + MAXBLK;          // BL

    const int nfused = BL / TM + N_AA;

    prep_kernel<<<31, 1024, 0, stream>>>(seq, aa_emb, ch_emb, W1, BL,
                                         aaT, chT, bucket_start, blk_type, blk_chunk, rowidx);
    fused_kernel<<<nfused, 256, 0, stream>>>(chain, xyz, dihed, orient,
                                             W1, b1, W2, b2, W3, b3, W4, b4,
                                             aaT, chT, bucket_start, blk_type, blk_chunk, rowidx,
                                             out);
}

// Round 7
// 132.355 us; speedup vs baseline: 1.8496x; 1.8496x over previous
//
#include <hip/hip_runtime.h>
#include <math.h>

#define N_AA    20
#define NATOM   15
#define TM      16
#define MAXBL   16384
#define MAXBLK  (MAXBL / TM + N_AA)   // 1044
#define NWAVE   16

#define FSX  104   // feat LDS stride (bf16): 208 B rows, 16B aligned, 2-way conflicts only
#define HSX  264   // hA stride (bf16): 528 B rows
#define H2SX 136   // hB stride (bf16): 272 B rows

typedef __attribute__((ext_vector_type(8))) short bf16x8;
typedef __attribute__((ext_vector_type(4))) float f32x4;

#define W1F_SLOTS  (N_AA * 16 * 3 * 64)   // 61440 fragment slots (8 bf16 each)
#define W2F_SLOTS  (8 * 8 * 64)           // 4096
#define W34F_SLOTS (8 * 4 * 64)           // 2048
#define TOT_SLOTS  (W1F_SLOTS + W2F_SLOTS + 2 * W34F_SLOTS)  // 69632

__device__ __forceinline__ unsigned short f2bf(float x) {
    unsigned u = __float_as_uint(x);
    return (unsigned short)((u + 0x7FFFu + ((u >> 16) & 1u)) >> 16);   // RNE
}
__device__ __forceinline__ float bf2f(unsigned short h) {
    return __uint_as_float(((unsigned)h) << 16);
}
__device__ __forceinline__ void put2(unsigned short* H, unsigned short* L, int idx, float v) {
    unsigned short hi = f2bf(v);
    H[idx] = hi;
    L[idx] = f2bf(v - bf2f(hi));
}

// ---------------- prep: blocks 0..29 tables, 30 sort, 31.. weight-fragment packing ----------------
__global__ __launch_bounds__(1024) void prep_kernel(
    const int* __restrict__ seq, const float* __restrict__ aa_emb,
    const float* __restrict__ chain_emb, const float* __restrict__ W1,
    const float* __restrict__ W2, const float* __restrict__ W3, const float* __restrict__ W4,
    int BL,
    float* __restrict__ aaT, float* __restrict__ chT,
    int* __restrict__ bucket_start, int* __restrict__ blk_type,
    int* __restrict__ blk_chunk, int* __restrict__ rowidx,
    unsigned short* __restrict__ W1fH, unsigned short* __restrict__ W1fL,
    unsigned short* __restrict__ W2fH, unsigned short* __restrict__ W2fL,
    unsigned short* __restrict__ W3fH, unsigned short* __restrict__ W3fL,
    unsigned short* __restrict__ W4fH, unsigned short* __restrict__ W4fL)
{
    const int t = threadIdx.x;
    const int b = blockIdx.x;

    if (b < 30) {                       // aaT / chT tables (fp32)
        if (t < 256) {
            if (b < N_AA) {
                const float* e = aa_emb + b * 128;
                float acc = 0.f;
                #pragma unroll 8
                for (int k = 0; k < 128; ++k)
                    acc += e[k] * W1[(size_t)k * 256 + t];
                aaT[b * 256 + t] = acc;
            } else {
                const int c = b - N_AA;
                const float* e = chain_emb + c * 128;
                float acc = 0.f;
                #pragma unroll 8
                for (int k = 0; k < 128; ++k)
                    acc += e[k] * W1[(size_t)(1067 + k) * 256 + t];
                chT[c * 256 + t] = acc;
            }
        }
        return;
    }

    if (b >= 31) {                      // weight fragment packing (bf16 hi/lo)
        const int slot = (b - 31) * 1024 + t;
        if (slot >= TOT_SLOTS) return;
        float v[8];
        unsigned short *dH, *dL;
        if (slot < W1F_SLOTS) {
            const int g = slot / 3072, r1 = slot % 3072;
            const int tile = r1 / 192, chunk = (r1 / 64) % 3, lane = r1 % 64;
            const int n  = tile * 16 + (lane & 15);
            const int kb = chunk * 32 + (lane >> 4) * 8;
            #pragma unroll
            for (int j = 0; j < 8; ++j) {
                const int k = kb + j;
                float x = 0.f;
                if (k < 45)       x = W1[(size_t)(128 + g * 45 + k) * 256 + n];
                else if (k < 84)  x = W1[(size_t)(1028 + k - 45) * 256 + n];
                v[j] = x;
            }
            dH = W1fH + (size_t)slot * 8; dL = W1fL + (size_t)slot * 8;
        } else if (slot < W1F_SLOTS + W2F_SLOTS) {
            const int s = slot - W1F_SLOTS;
            const int tile = s / 512, chunk = (s / 64) % 8, lane = s % 64;
            const int n  = tile * 16 + (lane & 15);
            const int kb = chunk * 32 + (lane >> 4) * 8;
            #pragma unroll
            for (int j = 0; j < 8; ++j) v[j] = W2[(size_t)(kb + j) * 128 + n];
            dH = W2fH + (size_t)s * 8; dL = W2fL + (size_t)s * 8;
        } else if (slot < W1F_SLOTS + W2F_SLOTS + W34F_SLOTS) {
            const int s = slot - W1F_SLOTS - W2F_SLOTS;
            const int tile = s / 256, chunk = (s / 64) % 4, lane = s % 64;
            const int n  = tile * 16 + (lane & 15);
            const int kb = chunk * 32 + (lane >> 4) * 8;
            #pragma unroll
            for (int j = 0; j < 8; ++j) v[j] = W3[(size_t)(kb + j) * 128 + n];
            dH = W3fH + (size_t)s * 8; dL = W3fL + (size_t)s * 8;
        } else {
            const int s = slot - W1F_SLOTS - W2F_SLOTS - W34F_SLOTS;
            const int tile = s / 256, chunk = (s / 64) % 4, lane = s % 64;
            const int n  = tile * 16 + (lane & 15);
            const int kb = chunk * 32 + (lane >> 4) * 8;
            #pragma unroll
            for (int j = 0; j < 8; ++j) v[j] = W4[(size_t)(kb + j) * 128 + n];
            dH = W4fH + (size_t)s * 8; dL = W4fL + (size_t)s * 8;
        }
        #pragma unroll
        for (int j = 0; j < 8; ++j) {
            const unsigned short hi = f2bf(v[j]);
            dH[j] = hi;
            dL[j] = f2bf(v[j] - bf2f(hi));
        }
        return;
    }

    // ---- block 30: counting sort of rows by aa type ----
    __shared__ int sseq[MAXBL];
    __shared__ int hist[NWAVE][N_AA];
    __shared__ int wcur[NWAVE][N_AA];
    __shared__ int bs[N_AA + 1];
    __shared__ int blkoff[N_AA + 1];

    const int w = t >> 6;
    for (int i = t; i < BL; i += 1024) sseq[i] = seq[i];
    if (t < NWAVE * N_AA) hist[t / N_AA][t % N_AA] = 0;
    __syncthreads();
    for (int i = t; i < BL; i += 1024) atomicAdd(&hist[w][sseq[i]], 1);
    __syncthreads();
    if (t == 0) {
        int runr = 0, runb = 0;
        for (int g = 0; g < N_AA; ++g) {
            int s = 0;
            #pragma unroll
            for (int ww = 0; ww < NWAVE; ++ww) s += hist[ww][g];
            bs[g] = runr; runr += s;
            blkoff[g] = runb; runb += (s + TM - 1) / TM;
        }
        bs[N_AA] = runr; blkoff[N_AA] = runb;
    }
    __syncthreads();
    if (t <= N_AA) bucket_start[t] = bs[t];
    if (t < NWAVE * N_AA) {
        const int w2 = t / N_AA, g2 = t % N_AA;
        int o = bs[g2];
        for (int ww = 0; ww < w2; ++ww) o += hist[ww][g2];
        wcur[w2][g2] = o;
    }
    const int nblk = blkoff[N_AA];
    for (int i = t; i < MAXBLK; i += 1024) {
        if (i < nblk) {
            int g = 0;
            while (blkoff[g + 1] <= i) ++g;
            blk_type[i]  = g;
            blk_chunk[i] = i - blkoff[g];
        } else blk_type[i] = -1;
    }
    __syncthreads();
    for (int i = t; i < BL; i += 1024) {
        const int pos = atomicAdd(&wcur[w][sseq[i]], 1);
        rowidx[pos] = i;
    }
}

// ---------------- fused: features + 4-layer MLP via MFMA, 16 same-type rows/block ----------------
__global__ __launch_bounds__(256, 4) void fused_kernel(
    const int* __restrict__ chain_idx, const float* __restrict__ xyz,
    const float* __restrict__ dihedrals, const float* __restrict__ orientation,
    const float* __restrict__ b1, const float* __restrict__ b2,
    const float* __restrict__ b3, const float* __restrict__ b4,
    const float* __restrict__ aaT, const float* __restrict__ chT,
    const int* __restrict__ bucket_start, const int* __restrict__ blk_type,
    const int* __restrict__ blk_chunk, const int* __restrict__ rowidx,
    const unsigned short* __restrict__ W1fH, const unsigned short* __restrict__ W1fL,
    const unsigned short* __restrict__ W2fH, const unsigned short* __restrict__ W2fL,
    const unsigned short* __restrict__ W3fH, const unsigned short* __restrict__ W3fL,
    const unsigned short* __restrict__ W4fH, const unsigned short* __restrict__ W4fL,
    float* __restrict__ out)
{
    __shared__ __align__(16) unsigned short featH[TM * FSX], featL[TM * FSX];
    __shared__ __align__(16) unsigned short hAH[TM * HSX],  hAL[TM * HSX];
    __shared__ __align__(16) unsigned short hBH[TM * H2SX], hBL[TM * H2SX];
    __shared__ int s_row[TM], s_rowld[TM], s_chain[TM];

    const int t = threadIdx.x;
    const int g = blk_type[blockIdx.x];
    if (g < 0) return;
    const int chunk  = blk_chunk[blockIdx.x];
    const int bstart = bucket_start[g] + chunk * TM;
    const int nrows  = min(TM, bucket_start[g + 1] - bstart);

    if (t < TM) {
        const bool valid = (t < nrows);
        const int rl = rowidx[valid ? (bstart + t) : bstart];
        s_row[t]   = valid ? rl : -1;
        s_rowld[t] = rl;
        s_chain[t] = chain_idx[rl];
    }
    __syncthreads();

    // ---- features -> bf16 hi/lo in LDS. k map: 0..44 coords, 45..83 dih, 84..95 zero ----
    if (t < TM * NATOM) {
        const int r = t / NATOM, a = t % NATOM;
        const int rl = s_rowld[r];
        const float* xr = xyz + (size_t)rl * (NATOM * 3);
        const float cax = xr[3], cay = xr[4], caz = xr[5];   // CA_IDX = 1
        const float rx = xr[a*3+0] - cax;
        const float ry = xr[a*3+1] - cay;
        const float rz = xr[a*3+2] - caz;
        const float* O = orientation + (size_t)rl * 9;
        put2(featH, featL, r * FSX + a*3 + 0, O[0]*rx + O[3]*ry + O[6]*rz);
        put2(featH, featL, r * FSX + a*3 + 1, O[1]*rx + O[4]*ry + O[7]*rz);
        put2(featH, featL, r * FSX + a*3 + 2, O[2]*rx + O[5]*ry + O[8]*rz);
    }
    if (t < TM * 3) {
        const int r = t / 3, d = t % 3;
        const float x = dihedrals[(size_t)s_rowld[r] * 3 + d];
        const int base = r * FSX + 45 + d * 13;
        const float F3 = (float)(1.0 / 3.0);
        put2(featH, featL, base + 0, x);
        put2(featH, featL, base + 1, sinf(x));      put2(featH, featL, base + 2, sinf(2.f*x));
        put2(featH, featL, base + 3, sinf(3.f*x));  put2(featH, featL, base + 4, sinf(x));
        put2(featH, featL, base + 5, sinf(0.5f*x)); put2(featH, featL, base + 6, sinf(F3*x));
        put2(featH, featL, base + 7, cosf(x));      put2(featH, featL, base + 8, cosf(2.f*x));
        put2(featH, featL, base + 9, cosf(3.f*x));  put2(featH, featL, base +10, cosf(x));
        put2(featH, featL, base +11, cosf(0.5f*x)); put2(featH, featL, base +12, cosf(F3*x));
    }
    if (t < TM) {
        #pragma unroll
        for (int k = 84; k < 96; ++k) { featH[t * FSX + k] = 0; featL[t * FSX + k] = 0; }
    }
    __syncthreads();

    const int wave = t >> 6, lane = t & 63, quad = lane >> 4, nid = lane & 15;
    const f32x4 zero = {0.f, 0.f, 0.f, 0.f};

    // ---- layer 1: h1[16][256] = relu(feat @ W1g + b1 + aaT + chT); K=96 (3 chunks), 4 tiles/wave ----
    {
        f32x4 acc[4] = {zero, zero, zero, zero};
        for (int c = 0; c < 3; ++c) {
            const bf16x8 aH = *(const bf16x8*)(featH + nid * FSX + c * 32 + quad * 8);
            const bf16x8 aL = *(const bf16x8*)(featL + nid * FSX + c * 32 + quad * 8);
            #pragma unroll
            for (int tt = 0; tt < 4; ++tt) {
                const size_t off = ((size_t)((g * 16 + (wave * 4 + tt)) * 3 + c) * 64 + lane) * 8;
                const bf16x8 bH = *(const bf16x8*)(W1fH + off);
                const bf16x8 bL = *(const bf16x8*)(W1fL + off);
                acc[tt] = __builtin_amdgcn_mfma_f32_16x16x32_bf16(aH, bH, acc[tt], 0, 0, 0);
                acc[tt] = __builtin_amdgcn_mfma_f32_16x16x32_bf16(aH, bL, acc[tt], 0, 0, 0);
                acc[tt] = __builtin_amdgcn_mfma_f32_16x16x32_bf16(aL, bH, acc[tt], 0, 0, 0);
            }
        }
        #pragma unroll
        for (int tt = 0; tt < 4; ++tt) {
            const int j = (wave * 4 + tt) * 16 + nid;
            const float cb = b1[j] + aaT[g * 256 + j];
            #pragma unroll
            for (int r = 0; r < 4; ++r) {
                const int row = quad * 4 + r;
                float v = acc[tt][r] + cb + chT[s_chain[row] * 256 + j];
                v = fmaxf(v, 0.f);
                put2(hAH, hAL, row * HSX + j, v);
            }
        }
    }
    __syncthreads();

    // ---- layer 2: h2[16][128] = relu(h1 @ W2 + b2); K=256 (8 chunks), 2 tiles/wave ----
    {
        f32x4 acc[2] = {zero, zero};
        for (int c = 0; c < 8; ++c) {
            const bf16x8 aH = *(const bf16x8*)(hAH + nid * HSX + c * 32 + quad * 8);
            const bf16x8 aL = *(const bf16x8*)(hAL + nid * HSX + c * 32 + quad * 8);
            #pragma unroll
            for (int tt = 0; tt < 2; ++tt) {
                const size_t off = ((size_t)((wave * 2 + tt) * 8 + c) * 64 + lane) * 8;
                const bf16x8 bH = *(const bf16x8*)(W2fH + off);
                const bf16x8 bL = *(const bf16x8*)(W2fL + off);
                acc[tt] = __builtin_amdgcn_mfma_f32_16x16x32_bf16(aH, bH, acc[tt], 0, 0, 0);
                acc[tt] = __builtin_amdgcn_mfma_f32_16x16x32_bf16(aH, bL, acc[tt], 0, 0, 0);
                acc[tt] = __builtin_amdgcn_mfma_f32_16x16x32_bf16(aL, bH, acc[tt], 0, 0, 0);
            }
        }
        #pragma unroll
        for (int tt = 0; tt < 2; ++tt) {
            const int j = (wave * 2 + tt) * 16 + nid;
            const float bb = b2[j];
            #pragma unroll
            for (int r = 0; r < 4; ++r) {
                const int row = quad * 4 + r;
                float v = fmaxf(acc[tt][r] + bb, 0.f);
                put2(hBH, hBL, row * H2SX + j, v);
            }
        }
    }
    __syncthreads();

    // ---- layer 3: h3[16][128] = relu(h2 @ W3 + b3); K=128 (4 chunks) -> hA (cols 0..127) ----
    {
        f32x4 acc[2] = {zero, zero};
        for (int c = 0; c < 4; ++c) {
            const bf16x8 aH = *(const bf16x8*)(hBH + nid * H2SX + c * 32 + quad * 8);
            const bf16x8 aL = *(const bf16x8*)(hBL + nid * H2SX + c * 32 + quad * 8);
            #pragma unroll
            for (int tt = 0; tt < 2; ++tt) {
                const size_t off = ((size_t)((wave * 2 + tt) * 4 + c) * 64 + lane) * 8;
                const bf16x8 bH = *(const bf16x8*)(W3fH + off);
                const bf16x8 bL = *(const bf16x8*)(W3fL + off);
                acc[tt] = __builtin_amdgcn_mfma_f32_16x16x32_bf16(aH, bH, acc[tt], 0, 0, 0);
                acc[tt] = __builtin_amdgcn_mfma_f32_16x16x32_bf16(aH, bL, acc[tt], 0, 0, 0);
                acc[tt] = __builtin_amdgcn_mfma_f32_16x16x32_bf16(aL, bH, acc[tt], 0, 0, 0);
            }
        }
        #pragma unroll
        for (int tt = 0; tt < 2; ++tt) {
            const int j = (wave * 2 + tt) * 16 + nid;
            const float bb = b3[j];
            #pragma unroll
            for (int r = 0; r < 4; ++r) {
                const int row = quad * 4 + r;
                float v = fmaxf(acc[tt][r] + bb, 0.f);
                put2(hAH, hAL, row * HSX + j, v);
            }
        }
    }
    __syncthreads();

    // ---- layer 4: out = h3 @ W4 + b4; scatter fp32 to original rows ----
    {
        f32x4 acc[2] = {zero, zero};
        for (int c = 0; c < 4; ++c) {
            const bf16x8 aH = *(const bf16x8*)(hAH + nid * HSX + c * 32 + quad * 8);
            const bf16x8 aL = *(const bf16x8*)(hAL + nid * HSX + c * 32 + quad * 8);
            #pragma unroll
            for (int tt = 0; tt < 2; ++tt) {
                const size_t off = ((size_t)((wave * 2 + tt) * 4 + c) * 64 + lane) * 8;
                const bf16x8 bH = *(const bf16x8*)(W4fH + off);
                const bf16x8 bL = *(const bf16x8*)(W4fL + off);
                acc[tt] = __builtin_amdgcn_mfma_f32_16x16x32_bf16(aH, bH, acc[tt], 0, 0, 0);
                acc[tt] = __builtin_amdgcn_mfma_f32_16x16x32_bf16(aH, bL, acc[tt], 0, 0, 0);
                acc[tt] = __builtin_amdgcn_mfma_f32_16x16x32_bf16(aL, bH, acc[tt], 0, 0, 0);
            }
        }
        #pragma unroll
        for (int tt = 0; tt < 2; ++tt) {
            const int j = (wave * 2 + tt) * 16 + nid;
            const float bb = b4[j];
            #pragma unroll
            for (int r = 0; r < 4; ++r) {
                const int row = quad * 4 + r;
                const int orow = s_row[row];
                if (orow >= 0) out[(size_t)orow * 128 + j] = acc[tt][r] + bb;
            }
        }
    }
}

extern "C" void kernel_launch(void* const* d_in, const int* in_sizes, int n_in,
                              void* d_out, int out_size, void* d_ws, size_t ws_size,
                              hipStream_t stream) {
    const int*   seq    = (const int*)d_in[0];
    const float* xyz    = (const float*)d_in[1];
    const float* dihed  = (const float*)d_in[2];
    const int*   chain  = (const int*)d_in[3];
    const float* orient = (const float*)d_in[4];
    // d_in[5] = atom_mask: unused by the reference
    const float* aa_emb = (const float*)d_in[6];
    const float* ch_emb = (const float*)d_in[7];
    const float* W1 = (const float*)d_in[8];
    const float* b1 = (const float*)d_in[9];
    const float* W2 = (const float*)d_in[10];
    const float* b2 = (const float*)d_in[11];
    const float* W3 = (const float*)d_in[12];
    const float* b3 = (const float*)d_in[13];
    const float* W4 = (const float*)d_in[14];
    const float* b4 = (const float*)d_in[15];
    float* out = (float*)d_out;

    const int BL = in_sizes[0];           // 16384 rows

    // workspace layout
    char* p = (char*)d_ws;
    float* aaT = (float*)p;            p += 20 * 256 * 4;
    float* chT = (float*)p;            p += 10 * 256 * 4;
    int* bucket_start = (int*)p;       p += 32 * 4;
    int* blk_type     = (int*)p;       p += MAXBLK * 4;
    int* blk_chunk    = (int*)p;       p += MAXBLK * 4;
    int* rowidx       = (int*)p;       p += MAXBL * 4;
    p += ((16 - ((uintptr_t)p & 15)) & 15);
    unsigned short* W1fH = (unsigned short*)p; p += (size_t)W1F_SLOTS * 8 * 2;
    unsigned short* W1fL = (unsigned short*)p; p += (size_t)W1F_SLOTS * 8 * 2;
    unsigned short* W2fH = (unsigned short*)p; p += (size_t)W2F_SLOTS * 8 * 2;
    unsigned short* W2fL = (unsigned short*)p; p += (size_t)W2F_SLOTS * 8 * 2;
    unsigned short* W3fH = (unsigned short*)p; p += (size_t)W34F_SLOTS * 8 * 2;
    unsigned short* W3fL = (unsigned short*)p; p += (size_t)W34F_SLOTS * 8 * 2;
    unsigned short* W4fH = (unsigned short*)p; p += (size_t)W34F_SLOTS * 8 * 2;
    unsigned short* W4fL = (unsigned short*)p;

    const int nprep  = 31 + (TOT_SLOTS + 1023) / 1024;   // 99 blocks
    const int nfused = BL / TM + N_AA;                   // 1044

    prep_kernel<<<nprep, 1024, 0, stream>>>(seq, aa_emb, ch_emb, W1, W2, W3, W4, BL,
                                            aaT, chT, bucket_start, blk_type, blk_chunk, rowidx,
                                            W1fH, W1fL, W2fH, W2fL, W3fH, W3fL, W4fH, W4fL);
    fused_kernel<<<nfused, 256, 0, stream>>>(chain, xyz, dihed, orient,
                                             b1, b2, b3, b4, aaT, chT,
                                             bucket_start, blk_type, blk_chunk, rowidx,
                                             W1fH, W1fL, W2fH, W2fL, W3fH, W3fL, W4fH, W4fL,
                                             out);
}

// Round 8
// 121.941 us; speedup vs baseline: 2.0076x; 1.0854x over previous
//
#include <hip/hip_runtime.h>
#include <math.h>

#define N_AA    20
#define NATOM   15
#define TM      16
#define MAXBL   16384
#define MAXBLK  (MAXBL / TM + N_AA)   // 1044
#define NWAVE   16

#define FSX  104   // feat LDS stride (bf16)
#define HSX  264   // hA stride (bf16)
#define H2SX 136   // hB stride (bf16)

typedef __attribute__((ext_vector_type(8))) short bf16x8;
typedef __attribute__((ext_vector_type(4))) float f32x4;

#define W1F_SLOTS  (N_AA * 16 * 3 * 64)   // 61440 fragment slots (8 bf16 each)
#define W2F_SLOTS  (8 * 8 * 64)           // 4096
#define W34F_SLOTS (8 * 4 * 64)           // 2048
#define TOT_SLOTS  (W1F_SLOTS + W2F_SLOTS + 2 * W34F_SLOTS)  // 69632

__device__ __forceinline__ unsigned short f2bf(float x) {
    unsigned u = __float_as_uint(x);
    return (unsigned short)((u + 0x7FFFu + ((u >> 16) & 1u)) >> 16);   // RNE
}
__device__ __forceinline__ float bf2f(unsigned short h) {
    return __uint_as_float(((unsigned)h) << 16);
}
__device__ __forceinline__ void put2(unsigned short* H, unsigned short* L, int idx, float v) {
    unsigned short hi = f2bf(v);
    H[idx] = hi;
    L[idx] = f2bf(v - bf2f(hi));
}

// ---------------- prep: blocks 0..7 tables (4 each), 8 sort, 9.. weight-fragment packing ----------------
__global__ __launch_bounds__(1024) void prep_kernel(
    const int* __restrict__ seq, const float* __restrict__ aa_emb,
    const float* __restrict__ chain_emb, const float* __restrict__ W1,
    const float* __restrict__ W2, const float* __restrict__ W3, const float* __restrict__ W4,
    int BL,
    float* __restrict__ aaT, float* __restrict__ chT,
    int* __restrict__ bucket_start, int* __restrict__ blk_type,
    int* __restrict__ blk_chunk, int* __restrict__ rowidx,
    unsigned short* __restrict__ W1fH, unsigned short* __restrict__ W1fL,
    unsigned short* __restrict__ W2fH, unsigned short* __restrict__ W2fL,
    unsigned short* __restrict__ W3fH, unsigned short* __restrict__ W3fL,
    unsigned short* __restrict__ W4fH, unsigned short* __restrict__ W4fL)
{
    const int t = threadIdx.x;
    const int b = blockIdx.x;

    if (b < 8) {                        // aaT / chT tables (fp32), 4 tables per block
        const int tab = b * 4 + (t >> 8);
        const int col = t & 255;
        if (tab < 30) {
            if (tab < N_AA) {
                const float* e = aa_emb + tab * 128;
                float acc = 0.f;
                #pragma unroll 8
                for (int k = 0; k < 128; ++k)
                    acc += e[k] * W1[(size_t)k * 256 + col];
                aaT[tab * 256 + col] = acc;
            } else {
                const int c = tab - N_AA;
                const float* e = chain_emb + c * 128;
                float acc = 0.f;
                #pragma unroll 8
                for (int k = 0; k < 128; ++k)
                    acc += e[k] * W1[(size_t)(1067 + k) * 256 + col];
                chT[c * 256 + col] = acc;
            }
        }
        return;
    }

    if (b >= 9) {                       // weight fragment packing (bf16 hi/lo)
        const int slot = (b - 9) * 1024 + t;
        if (slot >= TOT_SLOTS) return;
        float v[8];
        unsigned short *dH, *dL;
        if (slot < W1F_SLOTS) {
            const int g = slot / 3072, r1 = slot % 3072;
            const int tile = r1 / 192, chunk = (r1 / 64) % 3, lane = r1 % 64;
            const int n  = tile * 16 + (lane & 15);
            const int kb = chunk * 32 + (lane >> 4) * 8;
            #pragma unroll
            for (int j = 0; j < 8; ++j) {
                const int k = kb + j;
                float x = 0.f;
                if (k < 45)       x = W1[(size_t)(128 + g * 45 + k) * 256 + n];
                else if (k < 84)  x = W1[(size_t)(1028 + k - 45) * 256 + n];
                v[j] = x;
            }
            dH = W1fH + (size_t)slot * 8; dL = W1fL + (size_t)slot * 8;
        } else if (slot < W1F_SLOTS + W2F_SLOTS) {
            const int s = slot - W1F_SLOTS;
            const int tile = s / 512, chunk = (s / 64) % 8, lane = s % 64;
            const int n  = tile * 16 + (lane & 15);
            const int kb = chunk * 32 + (lane >> 4) * 8;
            #pragma unroll
            for (int j = 0; j < 8; ++j) v[j] = W2[(size_t)(kb + j) * 128 + n];
            dH = W2fH + (size_t)s * 8; dL = W2fL + (size_t)s * 8;
        } else if (slot < W1F_SLOTS + W2F_SLOTS + W34F_SLOTS) {
            const int s = slot - W1F_SLOTS - W2F_SLOTS;
            const int tile = s / 256, chunk = (s / 64) % 4, lane = s % 64;
            const int n  = tile * 16 + (lane & 15);
            const int kb = chunk * 32 + (lane >> 4) * 8;
            #pragma unroll
            for (int j = 0; j < 8; ++j) v[j] = W3[(size_t)(kb + j) * 128 + n];
            dH = W3fH + (size_t)s * 8; dL = W3fL + (size_t)s * 8;
        } else {
            const int s = slot - W1F_SLOTS - W2F_SLOTS - W34F_SLOTS;
            const int tile = s / 256, chunk = (s / 64) % 4, lane = s % 64;
            const int n  = tile * 16 + (lane & 15);
            const int kb = chunk * 32 + (lane >> 4) * 8;
            #pragma unroll
            for (int j = 0; j < 8; ++j) v[j] = W4[(size_t)(kb + j) * 128 + n];
            dH = W4fH + (size_t)s * 8; dL = W4fL + (size_t)s * 8;
        }
        #pragma unroll
        for (int j = 0; j < 8; ++j) {
            const unsigned short hi = f2bf(v[j]);
            dH[j] = hi;
            dL[j] = f2bf(v[j] - bf2f(hi));
        }
        return;
    }

    // ---- block 8: counting sort of rows by aa type ----
    __shared__ int sseq[MAXBL];
    __shared__ int hist[NWAVE][N_AA];
    __shared__ int wcur[NWAVE][N_AA];
    __shared__ int bs[N_AA + 1];
    __shared__ int blkoff[N_AA + 1];

    const int w = t >> 6;
    for (int i = t; i < BL; i += 1024) sseq[i] = seq[i];
    if (t < NWAVE * N_AA) hist[t / N_AA][t % N_AA] = 0;
    __syncthreads();
    for (int i = t; i < BL; i += 1024) atomicAdd(&hist[w][sseq[i]], 1);
    __syncthreads();
    if (t == 0) {
        int runr = 0, runb = 0;
        for (int g = 0; g < N_AA; ++g) {
            int s = 0;
            #pragma unroll
            for (int ww = 0; ww < NWAVE; ++ww) s += hist[ww][g];
            bs[g] = runr; runr += s;
            blkoff[g] = runb; runb += (s + TM - 1) / TM;
        }
        bs[N_AA] = runr; blkoff[N_AA] = runb;
    }
    __syncthreads();
    if (t <= N_AA) bucket_start[t] = bs[t];
    if (t < NWAVE * N_AA) {
        const int w2 = t / N_AA, g2 = t % N_AA;
        int o = bs[g2];
        for (int ww = 0; ww < w2; ++ww) o += hist[ww][g2];
        wcur[w2][g2] = o;
    }
    const int nblk = blkoff[N_AA];
    for (int i = t; i < MAXBLK; i += 1024) {
        if (i < nblk) {
            int g = 0;
            while (blkoff[g + 1] <= i) ++g;
            blk_type[i]  = g;
            blk_chunk[i] = i - blkoff[g];
        } else blk_type[i] = -1;
    }
    __syncthreads();
    for (int i = t; i < BL; i += 1024) {
        const int pos = atomicAdd(&wcur[w][sseq[i]], 1);
        rowidx[pos] = i;
    }
}

// ---------------- fused: features + 4-layer MLP via MFMA, 16 same-type rows/block ----------------
// LDS: hA (16.9 KB) + union(feat 6.6 KB | hB 8.7 KB) = 25.6 KB -> 5-6 blocks/CU
__global__ __launch_bounds__(256, 5) void fused_kernel(
    const int* __restrict__ chain_idx, const float* __restrict__ xyz,
    const float* __restrict__ dihedrals, const float* __restrict__ orientation,
    const float* __restrict__ b1, const float* __restrict__ b2,
    const float* __restrict__ b3, const float* __restrict__ b4,
    const float* __restrict__ aaT, const float* __restrict__ chT,
    const int* __restrict__ bucket_start, const int* __restrict__ blk_type,
    const int* __restrict__ blk_chunk, const int* __restrict__ rowidx,
    const unsigned short* __restrict__ W1fH, const unsigned short* __restrict__ W1fL,
    const unsigned short* __restrict__ W2fH, const unsigned short* __restrict__ W2fL,
    const unsigned short* __restrict__ W3fH, const unsigned short* __restrict__ W3fL,
    const unsigned short* __restrict__ W4fH, const unsigned short* __restrict__ W4fL,
    float* __restrict__ out)
{
    __shared__ __align__(16) unsigned short smemA[2 * TM * HSX];            // hA hi | hA lo
    __shared__ __align__(16) unsigned short smemB[2 * TM * H2SX];           // feat (hi|lo) then hB (hi|lo)
    __shared__ int s_row[TM], s_rowld[TM], s_chain[TM];

    unsigned short* hAH   = smemA;
    unsigned short* hAL   = smemA + TM * HSX;
    unsigned short* featH = smemB;                  // feat dead after layer 1
    unsigned short* featL = smemB + TM * FSX;
    unsigned short* hBH   = smemB;                  // hB written in layer-2 epilogue (post-barrier)
    unsigned short* hBL   = smemB + TM * H2SX;

    const int t = threadIdx.x;
    const int g = blk_type[blockIdx.x];
    if (g < 0) return;
    const int chunk  = blk_chunk[blockIdx.x];
    const int bstart = bucket_start[g] + chunk * TM;
    const int nrows  = min(TM, bucket_start[g + 1] - bstart);

    if (t < TM) {
        const bool valid = (t < nrows);
        const int rl = rowidx[valid ? (bstart + t) : bstart];
        s_row[t]   = valid ? rl : -1;
        s_rowld[t] = rl;
        s_chain[t] = chain_idx[rl];
    }
    __syncthreads();

    // ---- features -> bf16 hi/lo in LDS. k map: 0..44 coords, 45..83 dih, 84..95 zero ----
    if (t < TM * NATOM) {
        const int r = t / NATOM, a = t % NATOM;
        const int rl = s_rowld[r];
        const float* xr = xyz + (size_t)rl * (NATOM * 3);
        const float cax = xr[3], cay = xr[4], caz = xr[5];   // CA_IDX = 1
        const float rx = xr[a*3+0] - cax;
        const float ry = xr[a*3+1] - cay;
        const float rz = xr[a*3+2] - caz;
        const float* O = orientation + (size_t)rl * 9;
        put2(featH, featL, r * FSX + a*3 + 0, O[0]*rx + O[3]*ry + O[6]*rz);
        put2(featH, featL, r * FSX + a*3 + 1, O[1]*rx + O[4]*ry + O[7]*rz);
        put2(featH, featL, r * FSX + a*3 + 2, O[2]*rx + O[5]*ry + O[8]*rz);
    }
    if (t < TM * 3) {
        const int r = t / 3, d = t % 3;
        const float x = dihedrals[(size_t)s_rowld[r] * 3 + d];
        const int base = r * FSX + 45 + d * 13;
        const float F3 = (float)(1.0 / 3.0);
        const float s1 = sinf(x), c1 = cosf(x);
        put2(featH, featL, base + 0, x);
        put2(featH, featL, base + 1, s1);           put2(featH, featL, base + 2, sinf(2.f*x));
        put2(featH, featL, base + 3, sinf(3.f*x));  put2(featH, featL, base + 4, s1);
        put2(featH, featL, base + 5, sinf(0.5f*x)); put2(featH, featL, base + 6, sinf(F3*x));
        put2(featH, featL, base + 7, c1);           put2(featH, featL, base + 8, cosf(2.f*x));
        put2(featH, featL, base + 9, cosf(3.f*x));  put2(featH, featL, base +10, c1);
        put2(featH, featL, base +11, cosf(0.5f*x)); put2(featH, featL, base +12, cosf(F3*x));
    }
    if (t < TM) {
        #pragma unroll
        for (int k = 84; k < 96; ++k) { featH[t * FSX + k] = 0; featL[t * FSX + k] = 0; }
    }
    __syncthreads();

    const int wave = t >> 6, lane = t & 63, quad = lane >> 4, nid = lane & 15;
    const f32x4 zero = {0.f, 0.f, 0.f, 0.f};

    // ---- layer 1: h1[16][256] = relu(feat @ W1g + b1 + aaT + chT); K=96 (3 chunks), 4 tiles/wave ----
    {
        f32x4 acc[4] = {zero, zero, zero, zero};
        for (int c = 0; c < 3; ++c) {
            const bf16x8 aH = *(const bf16x8*)(featH + nid * FSX + c * 32 + quad * 8);
            const bf16x8 aL = *(const bf16x8*)(featL + nid * FSX + c * 32 + quad * 8);
            #pragma unroll
            for (int tt = 0; tt < 4; ++tt) {
                const size_t off = ((size_t)((g * 16 + (wave * 4 + tt)) * 3 + c) * 64 + lane) * 8;
                const bf16x8 bH = *(const bf16x8*)(W1fH + off);
                const bf16x8 bL = *(const bf16x8*)(W1fL + off);
                acc[tt] = __builtin_amdgcn_mfma_f32_16x16x32_bf16(aH, bH, acc[tt], 0, 0, 0);
                acc[tt] = __builtin_amdgcn_mfma_f32_16x16x32_bf16(aH, bL, acc[tt], 0, 0, 0);
                acc[tt] = __builtin_amdgcn_mfma_f32_16x16x32_bf16(aL, bH, acc[tt], 0, 0, 0);
            }
        }
        #pragma unroll
        for (int tt = 0; tt < 4; ++tt) {
            const int j = (wave * 4 + tt) * 16 + nid;
            const float cb = b1[j] + aaT[g * 256 + j];
            #pragma unroll
            for (int r = 0; r < 4; ++r) {
                const int row = quad * 4 + r;
                float v = acc[tt][r] + cb + chT[s_chain[row] * 256 + j];
                v = fmaxf(v, 0.f);
                put2(hAH, hAL, row * HSX + j, v);
            }
        }
    }
    __syncthreads();   // h1 complete; ALL feat reads done -> hB may overwrite feat region

    // ---- layer 2: h2[16][128] = relu(h1 @ W2 + b2); K=256 (8 chunks), 2 tiles/wave ----
    {
        f32x4 acc[2] = {zero, zero};
        for (int c = 0; c < 8; ++c) {
            const bf16x8 aH = *(const bf16x8*)(hAH + nid * HSX + c * 32 + quad * 8);
            const bf16x8 aL = *(const bf16x8*)(hAL + nid * HSX + c * 32 + quad * 8);
            #pragma unroll
            for (int tt = 0; tt < 2; ++tt) {
                const size_t off = ((size_t)((wave * 2 + tt) * 8 + c) * 64 + lane) * 8;
                const bf16x8 bH = *(const bf16x8*)(W2fH + off);
                const bf16x8 bL = *(const bf16x8*)(W2fL + off);
                acc[tt] = __builtin_amdgcn_mfma_f32_16x16x32_bf16(aH, bH, acc[tt], 0, 0, 0);
                acc[tt] = __builtin_amdgcn_mfma_f32_16x16x32_bf16(aH, bL, acc[tt], 0, 0, 0);
                acc[tt] = __builtin_amdgcn_mfma_f32_16x16x32_bf16(aL, bH, acc[tt], 0, 0, 0);
            }
        }
        __syncthreads();   // all layer-2 LDS reads (hA) done; now safe to write hB over feat
        #pragma unroll
        for (int tt = 0; tt < 2; ++tt) {
            const int j = (wave * 2 + tt) * 16 + nid;
            const float bb = b2[j];
            #pragma unroll
            for (int r = 0; r < 4; ++r) {
                const int row = quad * 4 + r;
                float v = fmaxf(acc[tt][r] + bb, 0.f);
                put2(hBH, hBL, row * H2SX + j, v);
            }
        }
    }
    __syncthreads();

    // ---- layer 3: h3[16][128] = relu(h2 @ W3 + b3); K=128 (4 chunks) -> hA ----
    {
        f32x4 acc[2] = {zero, zero};
        for (int c = 0; c < 4; ++c) {
            const bf16x8 aH = *(const bf16x8*)(hBH + nid * H2SX + c * 32 + quad * 8);
            const bf16x8 aL = *(const bf16x8*)(hBL + nid * H2SX + c * 32 + quad * 8);
            #pragma unroll
            for (int tt = 0; tt < 2; ++tt) {
                const size_t off = ((size_t)((wave * 2 + tt) * 4 + c) * 64 + lane) * 8;
                const bf16x8 bH = *(const bf16x8*)(W3fH + off);
                const bf16x8 bL = *(const bf16x8*)(W3fL + off);
                acc[tt] = __builtin_amdgcn_mfma_f32_16x16x32_bf16(aH, bH, acc[tt], 0, 0, 0);
                acc[tt] = __builtin_amdgcn_mfma_f32_16x16x32_bf16(aH, bL, acc[tt], 0, 0, 0);
                acc[tt] = __builtin_amdgcn_mfma_f32_16x16x32_bf16(aL, bH, acc[tt], 0, 0, 0);
            }
        }
        #pragma unroll
        for (int tt = 0; tt < 2; ++tt) {
            const int j = (wave * 2 + tt) * 16 + nid;
            const float bb = b3[j];
            #pragma unroll
            for (int r = 0; r < 4; ++r) {
                const int row = quad * 4 + r;
                float v = fmaxf(acc[tt][r] + bb, 0.f);
                put2(hAH, hAL, row * HSX + j, v);
            }
        }
    }
    __syncthreads();

    // ---- layer 4: out = h3 @ W4 + b4; scatter fp32 to original rows ----
    {
        f32x4 acc[2] = {zero, zero};
        for (int c = 0; c < 4; ++c) {
            const bf16x8 aH = *(const bf16x8*)(hAH + nid * HSX + c * 32 + quad * 8);
            const bf16x8 aL = *(const bf16x8*)(hAL + nid * HSX + c * 32 + quad * 8);
            #pragma unroll
            for (int tt = 0; tt < 2; ++tt) {
                const size_t off = ((size_t)((wave * 2 + tt) * 4 + c) * 64 + lane) * 8;
                const bf16x8 bH = *(const bf16x8*)(W4fH + off);
                const bf16x8 bL = *(const bf16x8*)(W4fL + off);
                acc[tt] = __builtin_amdgcn_mfma_f32_16x16x32_bf16(aH, bH, acc[tt], 0, 0, 0);
                acc[tt] = __builtin_amdgcn_mfma_f32_16x16x32_bf16(aH, bL, acc[tt], 0, 0, 0);
                acc[tt] = __builtin_amdgcn_mfma_f32_16x16x32_bf16(aL, bH, acc[tt], 0, 0, 0);
            }
        }
        #pragma unroll
        for (int tt = 0; tt < 2; ++tt) {
            const int j = (wave * 2 + tt) * 16 + nid;
            const float bb = b4[j];
            #pragma unroll
            for (int r = 0; r < 4; ++r) {
                const int row = quad * 4 + r;
                const int orow = s_row[row];
                if (orow >= 0) out[(size_t)orow * 128 + j] = acc[tt][r] + bb;
            }
        }
    }
}

extern "C" void kernel_launch(void* const* d_in, const int* in_sizes, int n_in,
                              void* d_out, int out_size, void* d_ws, size_t ws_size,
                              hipStream_t stream) {
    const int*   seq    = (const int*)d_in[0];
    const float* xyz    = (const float*)d_in[1];
    const float* dihed  = (const float*)d_in[2];
    const int*   chain  = (const int*)d_in[3];
    const float* orient = (const float*)d_in[4];
    // d_in[5] = atom_mask: unused by the reference
    const float* aa_emb = (const float*)d_in[6];
    const float* ch_emb = (const float*)d_in[7];
    const float* W1 = (const float*)d_in[8];
    const float* b1 = (const float*)d_in[9];
    const float* W2 = (const float*)d_in[10];
    const float* b2 = (const float*)d_in[11];
    const float* W3 = (const float*)d_in[12];
    const float* b3 = (const float*)d_in[13];
    const float* W4 = (const float*)d_in[14];
    const float* b4 = (const float*)d_in[15];
    float* out = (float*)d_out;

    const int BL = in_sizes[0];           // 16384 rows

    // workspace layout
    char* p = (char*)d_ws;
    float* aaT = (float*)p;            p += 20 * 256 * 4;
    float* chT = (float*)p;            p += 10 * 256 * 4;
    int* bucket_start = (int*)p;       p += 32 * 4;
    int* blk_type     = (int*)p;       p += MAXBLK * 4;
    int* blk_chunk    = (int*)p;       p += MAXBLK * 4;
    int* rowidx       = (int*)p;       p += MAXBL * 4;
    p += ((16 - ((uintptr_t)p & 15)) & 15);
    unsigned short* W1fH = (unsigned short*)p; p += (size_t)W1F_SLOTS * 8 * 2;
    unsigned short* W1fL = (unsigned short*)p; p += (size_t)W1F_SLOTS * 8 * 2;
    unsigned short* W2fH = (unsigned short*)p; p += (size_t)W2F_SLOTS * 8 * 2;
    unsigned short* W2fL = (unsigned short*)p; p += (size_t)W2F_SLOTS * 8 * 2;
    unsigned short* W3fH = (unsigned short*)p; p += (size_t)W34F_SLOTS * 8 * 2;
    unsigned short* W3fL = (unsigned short*)p; p += (size_t)W34F_SLOTS * 8 * 2;
    unsigned short* W4fH = (unsigned short*)p; p += (size_t)W34F_SLOTS * 8 * 2;
    unsigned short* W4fL = (unsigned short*)p;

    const int nprep  = 9 + (TOT_SLOTS + 1023) / 1024;    // 77 blocks
    const int nfused = BL / TM + N_AA;                   // 1044

    prep_kernel<<<nprep, 1024, 0, stream>>>(seq, aa_emb, ch_emb, W1, W2, W3, W4, BL,
                                            aaT, chT, bucket_start, blk_type, blk_chunk, rowidx,
                                            W1fH, W1fL, W2fH, W2fL, W3fH, W3fL, W4fH, W4fL);
    fused_kernel<<<nfused, 256, 0, stream>>>(chain, xyz, dihed, orient,
                                             b1, b2, b3, b4, aaT, chT,
                                             bucket_start, blk_type, blk_chunk, rowidx,
                                             W1fH, W1fL, W2fH, W2fL, W3fH, W3fL, W4fH, W4fL,
                                             out);
}